// Round 1
// baseline (1714.971 us; speedup 1.0000x reference)
//
#include <hip/hip_runtime.h>
#include <hip/hip_bf16.h>

#define E_EDGES 1600000
#define NN 100000
#define HID 128
#define SCAN_B 391  // ceil(NN/256)

// ===========================================================================
// CSR build: counts -> exclusive scan -> permutation
// ===========================================================================
__global__ __launch_bounds__(256) void count_edges(const int* __restrict__ idx,
                                                   int* __restrict__ counts) {
  int e = blockIdx.x * 256 + threadIdx.x;
  if (e < E_EDGES) atomicAdd(&counts[idx[e]], 1);
}

__global__ __launch_bounds__(256) void scan_a(const int* __restrict__ counts,
                                              int* __restrict__ offsets,
                                              int* __restrict__ bsums) {
  __shared__ int s[256];
  int i = blockIdx.x * 256 + threadIdx.x;
  int v = (i < NN) ? counts[i] : 0;
  s[threadIdx.x] = v;
  __syncthreads();
  for (int d = 1; d < 256; d <<= 1) {
    int t = (threadIdx.x >= d) ? s[threadIdx.x - d] : 0;
    __syncthreads();
    s[threadIdx.x] += t;
    __syncthreads();
  }
  if (i < NN) offsets[i + 1] = s[threadIdx.x];  // inclusive within block
  if (threadIdx.x == 255) bsums[blockIdx.x] = s[255];
}

__global__ __launch_bounds__(512) void scan_b(int* __restrict__ bsums) {
  __shared__ int s[512];
  int t = threadIdx.x;
  int v = (t < SCAN_B) ? bsums[t] : 0;
  s[t] = v;
  __syncthreads();
  for (int d = 1; d < 512; d <<= 1) {
    int u = (t >= d) ? s[t - d] : 0;
    __syncthreads();
    s[t] += u;
    __syncthreads();
  }
  if (t < SCAN_B) bsums[t] = s[t] - v;  // exclusive block offsets
}

// scan_c now also initializes the scatter cursor (folds old cursor_init launch)
__global__ __launch_bounds__(256) void scan_c(int* __restrict__ offsets,
                                              const int* __restrict__ bsums,
                                              int* __restrict__ cursor) {
  int i = blockIdx.x * 256 + threadIdx.x;
  if (i < NN) {
    int v = offsets[i + 1] + bsums[blockIdx.x];
    offsets[i + 1] = v;
    if (i + 1 < NN) cursor[i + 1] = v;
  }
  if (i == 0) {
    offsets[0] = 0;
    cursor[0] = 0;
  }
}

__global__ __launch_bounds__(256) void scatter_perm(const int* __restrict__ idx,
                                                    int* __restrict__ cursor,
                                                    int* __restrict__ perm) {
  int e = blockIdx.x * 256 + threadIdx.x;
  if (e < E_EDGES) {
    int n = idx[e];
    int p = atomicAdd(&cursor[n], 1);
    perm[p] = e;
  }
}

// ===========================================================================
// Gather: one wave per node; lane owns dims {2l, 2l+1}. x row read coalesced
// (64 lanes x float2 = 512B), h written exactly once (no atomics, no memset).
// R2: manual 4-way unroll of the edge loop — 4 independent perm reads, 4
// independent rbf rows, 4 independent 512B x-row loads in flight per wave
// (was 1 — latency-serialized dependent chain of HBM misses).
// ===========================================================================
__global__ __launch_bounds__(256) void gather_nodes(
    const float* __restrict__ x, const float* __restrict__ rbf,
    const float* __restrict__ W_rbf, const int* __restrict__ offsets,
    const int* __restrict__ perm, float* __restrict__ h) {
  int wave = (int)((blockIdx.x * 256 + threadIdx.x) >> 6);
  int lane = threadIdx.x & 63;
  if (wave >= NN) return;
  int n = wave;
  int start = offsets[n], end = offsets[n + 1];

  float w0[6], w1[6];
#pragma unroll
  for (int k = 0; k < 6; ++k) {
    w0[k] = W_rbf[(2 * lane) * 6 + k];
    w1[k] = W_rbf[(2 * lane + 1) * 6 + k];
  }
  float a0 = 0.f, a1 = 0.f;

  int j = start;
  // 4-edge unrolled body: all loads independent -> 4 outstanding HBM reads
  for (; j + 4 <= end; j += 4) {
    int e0 = __builtin_amdgcn_readfirstlane(perm[j]);
    int e1 = __builtin_amdgcn_readfirstlane(perm[j + 1]);
    int e2 = __builtin_amdgcn_readfirstlane(perm[j + 2]);
    int e3 = __builtin_amdgcn_readfirstlane(perm[j + 3]);

    const float* rb0 = rbf + (size_t)e0 * 6;
    const float* rb1 = rbf + (size_t)e1 * 6;
    const float* rb2 = rbf + (size_t)e2 * 6;
    const float* rb3 = rbf + (size_t)e3 * 6;

    float2 xv0 = *(const float2*)(x + (size_t)e0 * HID + 2 * lane);
    float2 xv1 = *(const float2*)(x + (size_t)e1 * HID + 2 * lane);
    float2 xv2 = *(const float2*)(x + (size_t)e2 * HID + 2 * lane);
    float2 xv3 = *(const float2*)(x + (size_t)e3 * HID + 2 * lane);

    float r00 = rb0[0], r01 = rb0[1], r02 = rb0[2], r03 = rb0[3], r04 = rb0[4], r05 = rb0[5];
    float r10 = rb1[0], r11 = rb1[1], r12 = rb1[2], r13 = rb1[3], r14 = rb1[4], r15 = rb1[5];
    float r20 = rb2[0], r21 = rb2[1], r22 = rb2[2], r23 = rb2[3], r24 = rb2[4], r25 = rb2[5];
    float r30 = rb3[0], r31 = rb3[1], r32 = rb3[2], r33 = rb3[3], r34 = rb3[4], r35 = rb3[5];

    float g00 = r00 * w0[0] + r01 * w0[1] + r02 * w0[2] + r03 * w0[3] + r04 * w0[4] + r05 * w0[5];
    float g01 = r00 * w1[0] + r01 * w1[1] + r02 * w1[2] + r03 * w1[3] + r04 * w1[4] + r05 * w1[5];
    float g10 = r10 * w0[0] + r11 * w0[1] + r12 * w0[2] + r13 * w0[3] + r14 * w0[4] + r15 * w0[5];
    float g11 = r10 * w1[0] + r11 * w1[1] + r12 * w1[2] + r13 * w1[3] + r14 * w1[4] + r15 * w1[5];
    float g20 = r20 * w0[0] + r21 * w0[1] + r22 * w0[2] + r23 * w0[3] + r24 * w0[4] + r25 * w0[5];
    float g21 = r20 * w1[0] + r21 * w1[1] + r22 * w1[2] + r23 * w1[3] + r24 * w1[4] + r25 * w1[5];
    float g30 = r30 * w0[0] + r31 * w0[1] + r32 * w0[2] + r33 * w0[3] + r34 * w0[4] + r35 * w0[5];
    float g31 = r30 * w1[0] + r31 * w1[1] + r32 * w1[2] + r33 * w1[3] + r34 * w1[4] + r35 * w1[5];

    a0 += g00 * xv0.x + g10 * xv1.x + g20 * xv2.x + g30 * xv3.x;
    a1 += g01 * xv0.y + g11 * xv1.y + g21 * xv2.y + g31 * xv3.y;
  }
  // tail
  for (; j < end; ++j) {
    int e = __builtin_amdgcn_readfirstlane(perm[j]);
    const float* rb = rbf + (size_t)e * 6;
    float r0 = rb[0], r1 = rb[1], r2 = rb[2], r3 = rb[3], r4 = rb[4], r5 = rb[5];
    float2 xv = *(const float2*)(x + (size_t)e * HID + 2 * lane);
    float g0 = r0 * w0[0] + r1 * w0[1] + r2 * w0[2] + r3 * w0[3] + r4 * w0[4] + r5 * w0[5];
    float g1 = r0 * w1[0] + r1 * w1[1] + r2 * w1[2] + r3 * w1[3] + r4 * w1[4] + r5 * w1[5];
    a0 += g0 * xv.x;
    a1 += g1 * xv.y;
  }
  *(float2*)(h + (size_t)n * HID + 2 * lane) = make_float2(a0, a1);
}

// ===========================================================================
// Fallback (R1 path) if ws_size is too small for CSR scratch
// ===========================================================================
__global__ __launch_bounds__(256) void edge_gate_scatter(
    const float* __restrict__ x, const float* __restrict__ rbf,
    const int* __restrict__ idx, const float* __restrict__ W_rbf,
    float* __restrict__ h) {
  __shared__ float sW[HID * 6];
  for (int t = threadIdx.x; t < HID * 6; t += 256) sW[t] = W_rbf[t];
  __syncthreads();
  long long gid = (long long)blockIdx.x * 256 + threadIdx.x;
  long long e = gid >> 5;
  int c = (int)(gid & 31);
  if (e >= E_EDGES) return;
  const float* rb = rbf + e * 6;
  float r0 = rb[0], r1 = rb[1], r2 = rb[2], r3 = rb[3], r4 = rb[4], r5 = rb[5];
  float4 xv = ((const float4*)x)[e * 32 + c];
  int node = idx[e];
  float* hp = h + (long long)node * HID + c * 4;
  float xs[4] = {xv.x, xv.y, xv.z, xv.w};
#pragma unroll
  for (int j = 0; j < 4; ++j) {
    const float* w = &sW[(c * 4 + j) * 6];
    float g = r0 * w[0] + r1 * w[1] + r2 * w[2] + r3 * w[3] + r4 * w[4] + r5 * w[5];
    atomicAdd(hp + j, g * xs[j]);
  }
}

// ===========================================================================
// Phase 2: fused 4-layer MLP (unchanged — known correct)
// ===========================================================================
#define LDA 132

__global__ __launch_bounds__(256, 1) void node_mlp(
    const float* __restrict__ h_in,
    const float* __restrict__ W1, const float* __restrict__ b1,
    const float* __restrict__ W2, const float* __restrict__ b2,
    const float* __restrict__ W3, const float* __restrict__ b3,
    const float* __restrict__ Wout, float* __restrict__ out) {
  __shared__ float sA[HID * LDA];
  __shared__ float sW[HID * LDA];

  int tid = threadIdx.x;
  int n0 = blockIdx.x * HID;

  for (int q = tid; q < HID * 32; q += 256) {
    int r = q >> 5, c = q & 31;
    float4 v = make_float4(0.f, 0.f, 0.f, 0.f);
    if (n0 + r < NN) v = ((const float4*)h_in)[(size_t)(n0 + r) * 32 + c];
    *(float4*)&sA[r * LDA + c * 4] = v;
  }

  const float* Ws[4] = {W1, W2, W3, Wout};
  const float* bs[3] = {b1, b2, b3};
  int tx = tid & 15, ty = tid >> 4;

  for (int layer = 0; layer < 4; ++layer) {
    const float* Wl = Ws[layer];
    for (int q = tid; q < HID * 32; q += 256) {
      int r = q >> 5, c = q & 31;
      *(float4*)&sW[r * LDA + c * 4] = ((const float4*)Wl)[r * 32 + c];
    }
    __syncthreads();

    float acc[8][8];
#pragma unroll
    for (int l = 0; l < 8; ++l)
#pragma unroll
      for (int j = 0; j < 8; ++j) acc[l][j] = 0.f;

    for (int k = 0; k < HID; k += 4) {
      float4 af[8], wf[8];
#pragma unroll
      for (int l = 0; l < 8; ++l)
        af[l] = *(const float4*)&sA[(ty + 16 * l) * LDA + k];
#pragma unroll
      for (int j = 0; j < 8; ++j)
        wf[j] = *(const float4*)&sW[(tx + 16 * j) * LDA + k];
#pragma unroll
      for (int l = 0; l < 8; ++l)
#pragma unroll
        for (int j = 0; j < 8; ++j)
          acc[l][j] += af[l].x * wf[j].x + af[l].y * wf[j].y +
                       af[l].z * wf[j].z + af[l].w * wf[j].w;
    }
    __syncthreads();

    if (layer < 3) {
      float bv[8];
#pragma unroll
      for (int j = 0; j < 8; ++j) bv[j] = bs[layer][tx + 16 * j];
#pragma unroll
      for (int l = 0; l < 8; ++l)
#pragma unroll
        for (int j = 0; j < 8; ++j) {
          float z = acc[l][j] + bv[j];
          sA[(ty + 16 * l) * LDA + tx + 16 * j] = z / (1.f + __expf(-z));
        }
    } else {
#pragma unroll
      for (int l = 0; l < 8; ++l) {
        int n = n0 + ty + 16 * l;
        if (n < NN) {
#pragma unroll
          for (int j = 0; j < 8; ++j)
            out[(size_t)n * HID + tx + 16 * j] = acc[l][j];
        }
      }
    }
  }
}

extern "C" void kernel_launch(void* const* d_in, const int* in_sizes, int n_in,
                              void* d_out, int out_size, void* d_ws, size_t ws_size,
                              hipStream_t stream) {
  const float* x     = (const float*)d_in[0];
  const float* rbf   = (const float*)d_in[1];
  const int*   idx   = (const int*)d_in[2];
  const float* W_rbf = (const float*)d_in[3];
  const float* W1 = (const float*)d_in[4];
  const float* b1 = (const float*)d_in[5];
  const float* W2 = (const float*)d_in[6];
  const float* b2 = (const float*)d_in[7];
  const float* W3 = (const float*)d_in[8];
  const float* b3 = (const float*)d_in[9];
  const float* Wout = (const float*)d_in[10];
  float* out = (float*)d_out;

  // ws layout
  char* wp = (char*)d_ws;
  float* h = (float*)wp;                 wp += (size_t)NN * HID * sizeof(float);
  int* counts  = (int*)wp;               wp += (size_t)NN * sizeof(int);
  int* offsets = (int*)wp;               wp += (size_t)(NN + 1) * sizeof(int);
  int* cursor  = (int*)wp;               wp += (size_t)NN * sizeof(int);
  int* perm    = (int*)wp;               wp += (size_t)E_EDGES * sizeof(int);
  int* bsums   = (int*)wp;               wp += 512 * sizeof(int);
  size_t needed = (size_t)(wp - (char*)d_ws);

  int eblk = (E_EDGES + 255) / 256;   // 6250
  int nblk = (NN + 255) / 256;        // 391

  if (ws_size >= needed) {
    hipMemsetAsync(counts, 0, (size_t)NN * sizeof(int), stream);
    count_edges<<<eblk, 256, 0, stream>>>(idx, counts);
    scan_a<<<SCAN_B, 256, 0, stream>>>(counts, offsets, bsums);
    scan_b<<<1, 512, 0, stream>>>(bsums);
    scan_c<<<nblk, 256, 0, stream>>>(offsets, bsums, cursor);
    scatter_perm<<<eblk, 256, 0, stream>>>(idx, cursor, perm);
    int gblk = (NN * 64 + 255) / 256;  // 25000 blocks, 1 wave/node
    gather_nodes<<<gblk, 256, 0, stream>>>(x, rbf, W_rbf, offsets, perm, h);
  } else {
    // fallback: atomic scatter (R1 path)
    hipMemsetAsync(h, 0, (size_t)NN * HID * sizeof(float), stream);
    int eblocks = (E_EDGES * 32 + 255) / 256;
    edge_gate_scatter<<<eblocks, 256, 0, stream>>>(x, rbf, idx, W_rbf, h);
  }

  int mblocks = (NN + HID - 1) / HID;  // 782
  node_mlp<<<mblocks, 256, 0, stream>>>(h, W1, b1, W2, b2, W3, b3, Wout, out);
}

// Round 2
// 1651.627 us; speedup vs baseline: 1.0384x; 1.0384x over previous
//
#include <hip/hip_runtime.h>
#include <hip/hip_bf16.h>

#define E_EDGES 1600000
#define NN 100000
#define HID 128
#define SCAN_B 391  // ceil(NN/256)

// ===========================================================================
// CSR build: counts -> exclusive scan -> permutation
// ===========================================================================
__global__ __launch_bounds__(256) void count_edges(const int* __restrict__ idx,
                                                   int* __restrict__ counts) {
  int e = blockIdx.x * 256 + threadIdx.x;
  if (e < E_EDGES) atomicAdd(&counts[idx[e]], 1);
}

__global__ __launch_bounds__(256) void scan_a(const int* __restrict__ counts,
                                              int* __restrict__ offsets,
                                              int* __restrict__ bsums) {
  __shared__ int s[256];
  int i = blockIdx.x * 256 + threadIdx.x;
  int v = (i < NN) ? counts[i] : 0;
  s[threadIdx.x] = v;
  __syncthreads();
  for (int d = 1; d < 256; d <<= 1) {
    int t = (threadIdx.x >= d) ? s[threadIdx.x - d] : 0;
    __syncthreads();
    s[threadIdx.x] += t;
    __syncthreads();
  }
  if (i < NN) offsets[i + 1] = s[threadIdx.x];  // inclusive within block
  if (threadIdx.x == 255) bsums[blockIdx.x] = s[255];
}

__global__ __launch_bounds__(512) void scan_b(int* __restrict__ bsums) {
  __shared__ int s[512];
  int t = threadIdx.x;
  int v = (t < SCAN_B) ? bsums[t] : 0;
  s[t] = v;
  __syncthreads();
  for (int d = 1; d < 512; d <<= 1) {
    int u = (t >= d) ? s[t - d] : 0;
    __syncthreads();
    s[t] += u;
    __syncthreads();
  }
  if (t < SCAN_B) bsums[t] = s[t] - v;  // exclusive block offsets
}

// scan_c also initializes the scatter cursor (folds old cursor_init launch)
__global__ __launch_bounds__(256) void scan_c(int* __restrict__ offsets,
                                              const int* __restrict__ bsums,
                                              int* __restrict__ cursor) {
  int i = blockIdx.x * 256 + threadIdx.x;
  if (i < NN) {
    int v = offsets[i + 1] + bsums[blockIdx.x];
    offsets[i + 1] = v;
    if (i + 1 < NN) cursor[i + 1] = v;
  }
  if (i == 0) {
    offsets[0] = 0;
    cursor[0] = 0;
  }
}

__global__ __launch_bounds__(256) void scatter_perm(const int* __restrict__ idx,
                                                    int* __restrict__ cursor,
                                                    int* __restrict__ perm) {
  int e = blockIdx.x * 256 + threadIdx.x;
  if (e < E_EDGES) {
    int n = idx[e];
    int p = atomicAdd(&cursor[n], 1);
    perm[p] = e;
  }
}

// ===========================================================================
// Gather: one wave per node; lane owns dims {2l, 2l+1}. x row read coalesced
// (64 lanes x float2 = 512B), h written exactly once (no atomics, no memset).
// R3: 8-deep group (8 independent 512B x-row loads in flight), rbf rows as
// 3x float2, and 4/2/1 tail cascade instead of serial singles.
// ===========================================================================
template <int W>
__device__ __forceinline__ void gather_group(
    const float* __restrict__ x, const float* __restrict__ rbf,
    const int* __restrict__ perm, int j, int lane,
    const float* w0, const float* w1, float& a0, float& a1) {
  int e[W];
#pragma unroll
  for (int t = 0; t < W; ++t) e[t] = __builtin_amdgcn_readfirstlane(perm[j + t]);
  float2 xv[W], r01[W], r23[W], r45[W];
#pragma unroll
  for (int t = 0; t < W; ++t) {
    const float* rb = rbf + (size_t)e[t] * 6;
    r01[t] = *(const float2*)(rb);
    r23[t] = *(const float2*)(rb + 2);
    r45[t] = *(const float2*)(rb + 4);
    xv[t] = *(const float2*)(x + (size_t)e[t] * HID + 2 * lane);
  }
#pragma unroll
  for (int t = 0; t < W; ++t) {
    float g0 = r01[t].x * w0[0] + r01[t].y * w0[1] + r23[t].x * w0[2] +
               r23[t].y * w0[3] + r45[t].x * w0[4] + r45[t].y * w0[5];
    float g1 = r01[t].x * w1[0] + r01[t].y * w1[1] + r23[t].x * w1[2] +
               r23[t].y * w1[3] + r45[t].x * w1[4] + r45[t].y * w1[5];
    a0 += g0 * xv[t].x;
    a1 += g1 * xv[t].y;
  }
}

__global__ __launch_bounds__(256) void gather_nodes(
    const float* __restrict__ x, const float* __restrict__ rbf,
    const float* __restrict__ W_rbf, const int* __restrict__ offsets,
    const int* __restrict__ perm, float* __restrict__ h) {
  int wave = (int)((blockIdx.x * 256 + threadIdx.x) >> 6);
  int lane = threadIdx.x & 63;
  if (wave >= NN) return;
  int n = wave;
  int start = offsets[n], end = offsets[n + 1];

  float w0[6], w1[6];
#pragma unroll
  for (int k = 0; k < 6; ++k) {
    w0[k] = W_rbf[(2 * lane) * 6 + k];
    w1[k] = W_rbf[(2 * lane + 1) * 6 + k];
  }
  float a0 = 0.f, a1 = 0.f;

  int j = start;
  for (; j + 8 <= end; j += 8)
    gather_group<8>(x, rbf, perm, j, lane, w0, w1, a0, a1);
  if (j + 4 <= end) {
    gather_group<4>(x, rbf, perm, j, lane, w0, w1, a0, a1);
    j += 4;
  }
  if (j + 2 <= end) {
    gather_group<2>(x, rbf, perm, j, lane, w0, w1, a0, a1);
    j += 2;
  }
  if (j < end)
    gather_group<1>(x, rbf, perm, j, lane, w0, w1, a0, a1);

  *(float2*)(h + (size_t)n * HID + 2 * lane) = make_float2(a0, a1);
}

// ===========================================================================
// Fallback (R1 path) if ws_size is too small for CSR scratch
// ===========================================================================
__global__ __launch_bounds__(256) void edge_gate_scatter(
    const float* __restrict__ x, const float* __restrict__ rbf,
    const int* __restrict__ idx, const float* __restrict__ W_rbf,
    float* __restrict__ h) {
  __shared__ float sW[HID * 6];
  for (int t = threadIdx.x; t < HID * 6; t += 256) sW[t] = W_rbf[t];
  __syncthreads();
  long long gid = (long long)blockIdx.x * 256 + threadIdx.x;
  long long e = gid >> 5;
  int c = (int)(gid & 31);
  if (e >= E_EDGES) return;
  const float* rb = rbf + e * 6;
  float r0 = rb[0], r1 = rb[1], r2 = rb[2], r3 = rb[3], r4 = rb[4], r5 = rb[5];
  float4 xv = ((const float4*)x)[e * 32 + c];
  int node = idx[e];
  float* hp = h + (long long)node * HID + c * 4;
  float xs[4] = {xv.x, xv.y, xv.z, xv.w};
#pragma unroll
  for (int j = 0; j < 4; ++j) {
    const float* w = &sW[(c * 4 + j) * 6];
    float g = r0 * w[0] + r1 * w[1] + r2 * w[2] + r3 * w[3] + r4 * w[4] + r5 * w[5];
    atomicAdd(hp + j, g * xs[j]);
  }
}

// ===========================================================================
// Phase 2: fused 4-layer MLP.
// R3: 512 threads/block (was 256) -> 8 waves/CU = 2 waves/SIMD at the same
// 135 KB LDS (still 1 block/CU). Same 128-node tile; per-thread acc 8x4.
// VALU floor unchanged; doubles latency hiding on LDS reads + barriers.
// ===========================================================================
#define LDA 132

__global__ __launch_bounds__(512, 2) void node_mlp(
    const float* __restrict__ h_in,
    const float* __restrict__ W1, const float* __restrict__ b1,
    const float* __restrict__ W2, const float* __restrict__ b2,
    const float* __restrict__ W3, const float* __restrict__ b3,
    const float* __restrict__ Wout, float* __restrict__ out) {
  __shared__ float sA[HID * LDA];
  __shared__ float sW[HID * LDA];

  int tid = threadIdx.x;
  int n0 = blockIdx.x * HID;

  for (int q = tid; q < HID * 32; q += 512) {
    int r = q >> 5, c = q & 31;
    float4 v = make_float4(0.f, 0.f, 0.f, 0.f);
    if (n0 + r < NN) v = ((const float4*)h_in)[(size_t)(n0 + r) * 32 + c];
    *(float4*)&sA[r * LDA + c * 4] = v;
  }

  const float* Ws[4] = {W1, W2, W3, Wout};
  const float* bs[3] = {b1, b2, b3};
  int tx = tid & 31, ty = tid >> 5;  // tx: out-col group (cols tx+32j), ty: row group (rows ty+16l)

  for (int layer = 0; layer < 4; ++layer) {
    const float* Wl = Ws[layer];
    for (int q = tid; q < HID * 32; q += 512) {
      int r = q >> 5, c = q & 31;
      *(float4*)&sW[r * LDA + c * 4] = ((const float4*)Wl)[r * 32 + c];
    }
    __syncthreads();

    float acc[8][4];
#pragma unroll
    for (int l = 0; l < 8; ++l)
#pragma unroll
      for (int j = 0; j < 4; ++j) acc[l][j] = 0.f;

    for (int k = 0; k < HID; k += 4) {
      float4 af[8], wf[4];
#pragma unroll
      for (int l = 0; l < 8; ++l)
        af[l] = *(const float4*)&sA[(ty + 16 * l) * LDA + k];
#pragma unroll
      for (int j = 0; j < 4; ++j)
        wf[j] = *(const float4*)&sW[(tx + 32 * j) * LDA + k];
#pragma unroll
      for (int l = 0; l < 8; ++l)
#pragma unroll
        for (int j = 0; j < 4; ++j)
          acc[l][j] += af[l].x * wf[j].x + af[l].y * wf[j].y +
                       af[l].z * wf[j].z + af[l].w * wf[j].w;
    }
    __syncthreads();

    if (layer < 3) {
      float bv[4];
#pragma unroll
      for (int j = 0; j < 4; ++j) bv[j] = bs[layer][tx + 32 * j];
#pragma unroll
      for (int l = 0; l < 8; ++l)
#pragma unroll
        for (int j = 0; j < 4; ++j) {
          float z = acc[l][j] + bv[j];
          sA[(ty + 16 * l) * LDA + tx + 32 * j] = z / (1.f + __expf(-z));
        }
    } else {
#pragma unroll
      for (int l = 0; l < 8; ++l) {
        int n = n0 + ty + 16 * l;
        if (n < NN) {
#pragma unroll
          for (int j = 0; j < 4; ++j)
            out[(size_t)n * HID + tx + 32 * j] = acc[l][j];
        }
      }
    }
  }
}

extern "C" void kernel_launch(void* const* d_in, const int* in_sizes, int n_in,
                              void* d_out, int out_size, void* d_ws, size_t ws_size,
                              hipStream_t stream) {
  const float* x     = (const float*)d_in[0];
  const float* rbf   = (const float*)d_in[1];
  const int*   idx   = (const int*)d_in[2];
  const float* W_rbf = (const float*)d_in[3];
  const float* W1 = (const float*)d_in[4];
  const float* b1 = (const float*)d_in[5];
  const float* W2 = (const float*)d_in[6];
  const float* b2 = (const float*)d_in[7];
  const float* W3 = (const float*)d_in[8];
  const float* b3 = (const float*)d_in[9];
  const float* Wout = (const float*)d_in[10];
  float* out = (float*)d_out;

  // ws layout
  char* wp = (char*)d_ws;
  float* h = (float*)wp;                 wp += (size_t)NN * HID * sizeof(float);
  int* counts  = (int*)wp;               wp += (size_t)NN * sizeof(int);
  int* offsets = (int*)wp;               wp += (size_t)(NN + 1) * sizeof(int);
  int* cursor  = (int*)wp;               wp += (size_t)NN * sizeof(int);
  int* perm    = (int*)wp;               wp += (size_t)E_EDGES * sizeof(int);
  int* bsums   = (int*)wp;               wp += 512 * sizeof(int);
  size_t needed = (size_t)(wp - (char*)d_ws);

  int eblk = (E_EDGES + 255) / 256;   // 6250
  int nblk = (NN + 255) / 256;        // 391

  if (ws_size >= needed) {
    hipMemsetAsync(counts, 0, (size_t)NN * sizeof(int), stream);
    count_edges<<<eblk, 256, 0, stream>>>(idx, counts);
    scan_a<<<SCAN_B, 256, 0, stream>>>(counts, offsets, bsums);
    scan_b<<<1, 512, 0, stream>>>(bsums);
    scan_c<<<nblk, 256, 0, stream>>>(offsets, bsums, cursor);
    scatter_perm<<<eblk, 256, 0, stream>>>(idx, cursor, perm);
    int gblk = (NN * 64 + 255) / 256;  // 25000 blocks, 1 wave/node
    gather_nodes<<<gblk, 256, 0, stream>>>(x, rbf, W_rbf, offsets, perm, h);
  } else {
    // fallback: atomic scatter (R1 path)
    hipMemsetAsync(h, 0, (size_t)NN * HID * sizeof(float), stream);
    int eblocks = (E_EDGES * 32 + 255) / 256;
    edge_gate_scatter<<<eblocks, 256, 0, stream>>>(x, rbf, idx, W_rbf, h);
  }

  int mblocks = (NN + HID - 1) / HID;  // 782
  node_mlp<<<mblocks, 512, 0, stream>>>(h, W1, b1, W2, b2, W3, b3, Wout, out);
}